// Round 7
// baseline (147.551 us; speedup 1.0000x reference)
//
#include <hip/hip_runtime.h>

#define NQ 16384
#define NB 128
#define NF 64
#define HD 128
#define EPSF 1e-8f
#define BTILE 4
#define NBT (NB / BTILE)   // 32 btiles

// ---------- helpers ----------
__device__ __forceinline__ float wave_allreduce_sum(float v) {
    #pragma unroll
    for (int m = 1; m < 64; m <<= 1) v += __shfl_xor(v, m, 64);
    return v;
}

// ---------- prep kernel: qvals (blocks 0..2047) + table (blocks 2048..2079) --
// qvals[q*NF + f] = float4{Qr, Qi, Qr^2+Qi^2, Qmag}
// tableD[f*NB + b] = float4(-2*Pr, -2*Pi, |P|^2+eps, -softplus(qw[b,f]))
// tableM[f*NB + b] = mw[b,f]
__global__ __launch_bounds__(256) void prep_kernel(
    const float* __restrict__ Q,        // [NQ][HD]
    const float* __restrict__ probes,   // [NB][HD]
    const float* __restrict__ angles,   // [NF]
    const float* __restrict__ qw,       // [NB][NF]
    const float* __restrict__ mw,       // [NB][NF]
    float4* __restrict__ qvals,         // [NQ][NF]
    float4* __restrict__ tableD,        // [NF][NB]
    float* __restrict__ tableM) {       // [NF][NB]
    if (blockIdx.x < 2048) {
        const int q  = blockIdx.x * 8 + (threadIdx.x >> 5);
        const int sl = threadIdx.x & 31;
        const float2* Q2 = (const float2*)Q;
        float2 a = Q2[q * 64 + sl];        // f = 2sl, 2sl+1 (real half)
        float2 c = Q2[q * 64 + 32 + sl];   // imag half
        float ss = a.x * a.x + a.y * a.y + c.x * c.x + c.y * c.y;
        #pragma unroll
        for (int m = 1; m < 32; m <<= 1) ss += __shfl_xor(ss, m);  // half-wave
        float inv = 1.0f / (sqrtf(ss) + EPSF);
        float Qr0 = a.x * inv, Qr1 = a.y * inv;
        float Qi0 = c.x * inv, Qi1 = c.y * inv;
        float B0 = Qr0 * Qr0 + Qi0 * Qi0;
        float B1 = Qr1 * Qr1 + Qi1 * Qi1;
        qvals[(size_t)q * NF + 2 * sl]     = make_float4(Qr0, Qi0, B0, sqrtf(B0 + EPSF));
        qvals[(size_t)q * NF + 2 * sl + 1] = make_float4(Qr1, Qi1, B1, sqrtf(B1 + EPSF));
    } else {
        const int b    = (blockIdx.x - 2048) * 4 + (threadIdx.x >> 6);
        const int lane = threadIdx.x & 63;   // == f
        float p0 = probes[b * HD + lane];
        float p1 = probes[b * HD + 64 + lane];
        float ss = wave_allreduce_sum(p0 * p0 + p1 * p1);
        float inv = 1.0f / (sqrtf(ss) + EPSF);
        float pr = p0 * inv, pi = p1 * inv;
        float ang = angles[lane];
        float cc = cosf(ang), sn = sinf(ang);
        float Pr = pr * cc - pi * sn;
        float Pi = pr * sn + pi * cc;
        float x = qw[b * NF + lane];
        float sp = (x > 0.0f) ? (x + log1pf(expf(-x))) : log1pf(expf(x));
        tableD[lane * NB + b] = make_float4(-2.0f * Pr, -2.0f * Pi,
                                            Pr * Pr + Pi * Pi + EPSF, -sp);
        tableM[lane * NB + b] = mw[b * NF + lane];
    }
}

// ---------- main kernel ----------
// lane = q (coalesced qvals b128 loads), BTILE=4 b's per block from LDS
// (broadcast reads, conflict-free). 2048 blocks -> 8 blocks/CU, 32 waves/CU
// (100% occupancy ceiling; round-3's BTILE=8 capped at 4 waves/SIMD and
// measured VALUBusy 57%). bt in LOW dispatch bits so blocks sharing a
// q-range run in the same window -> qvals re-reads hit L2/L3.
__global__ __launch_bounds__(256, 8) void main_kernel(
    const float4* __restrict__ tableD,  // [NF][NB]
    const float* __restrict__ tableM,   // [NF][NB]
    const float4* __restrict__ qvals,   // [NQ][NF]
    const float* __restrict__ bias,     // [NB]
    float* __restrict__ out) {          // [NQ][NB]
    __shared__ __align__(16) float4 ldsD[NF * BTILE];  // 4 KB
    __shared__ __align__(16) float  ldsM[NF * BTILE];  // 1 KB
    const int bt   = blockIdx.x & (NBT - 1);
    const int qblk = blockIdx.x / NBT;
    const int q = qblk * 256 + (int)threadIdx.x;

    // stage table: 256 float4 + 256 float, 1 each per thread
    {
        int idx = threadIdx.x;
        int f = idx >> 2, bb = idx & 3;
        ldsD[idx] = tableD[f * NB + bt * BTILE + bb];
        ldsM[idx] = tableM[f * NB + bt * BTILE + bb];
    }
    __syncthreads();

    float acc[BTILE];
    #pragma unroll
    for (int i = 0; i < BTILE; ++i) acc[i] = 0.0f;

    const float4* __restrict__ qp = qvals + (size_t)q * NF;

    #pragma unroll 4
    for (int f = 0; f < NF; ++f) {
        float4 qv = qp[f];                        // coalesced 16B/lane
        float4 tm4 = *(const float4*)&ldsM[f * BTILE];  // one b128, broadcast
        #pragma unroll
        for (int bb = 0; bb < BTILE; ++bb) {
            float4 td = ldsD[f * BTILE + bb];     // broadcast, conflict-free
            float t = td.z + qv.z;                // (|P|^2+eps) + |Qf|^2
            t = fmaf(td.y, qv.y, t);              // -2Pi*Qi
            t = fmaf(td.x, qv.x, t);              // -2Pr*Qr
            // analytically t >= eps; |.| guards rounding, folds into the
            // v_sqrt input modifier (free) -- replaces fmaxf (1 VOP saved)
            float d = __builtin_amdgcn_sqrtf(fabsf(t));
            float w = (&tm4.x)[bb];
            acc[bb] = fmaf(td.w, d, acc[bb]);
            acc[bb] = fmaf(w, qv.w, acc[bb]);
        }
    }

    #pragma unroll
    for (int bb = 0; bb < BTILE; ++bb) acc[bb] += bias[bt * BTILE + bb];
    float* op = out + (size_t)q * NB + bt * BTILE;
    *(float4*)op = make_float4(acc[0], acc[1], acc[2], acc[3]);
}

extern "C" void kernel_launch(void* const* d_in, const int* in_sizes, int n_in,
                              void* d_out, int out_size, void* d_ws, size_t ws_size,
                              hipStream_t stream) {
    const float* Q      = (const float*)d_in[0];   // [16384][128]
    const float* angles = (const float*)d_in[1];   // [64]
    const float* probes = (const float*)d_in[2];   // [128][128]
    const float* qw     = (const float*)d_in[3];   // [128][64]
    const float* mw     = (const float*)d_in[4];   // [128][64]
    const float* bias   = (const float*)d_in[5];   // [128]
    float* out = (float*)d_out;

    char* ws = (char*)d_ws;
    float4* tableD = (float4*)ws;                                    // 128 KB
    float*  tableM = (float*)(ws + NF * NB * sizeof(float4));        //  32 KB
    float4* qvals  = (float4*)(ws + NF * NB * sizeof(float4)
                                  + NF * NB * sizeof(float));        //  16 MB

    prep_kernel<<<2048 + NB / 4, 256, 0, stream>>>(Q, probes, angles, qw, mw,
                                                   qvals, tableD, tableM);
    main_kernel<<<(NQ / 256) * NBT, 256, 0, stream>>>(tableD, tableM, qvals, bias, out);
}

// Round 8
// 113.125 us; speedup vs baseline: 1.3043x; 1.3043x over previous
//
#include <hip/hip_runtime.h>

#define NQ 16384
#define NB 128
#define NF 64
#define HD 128
#define EPSF 1e-8f
#define BTILE 4            // b's per block
#define NBT (NB / BTILE)   // 32 btiles
#define QPT 4              // q's per thread

// ---------- helpers ----------
__device__ __forceinline__ float wave_allreduce_sum(float v) {
    #pragma unroll
    for (int m = 1; m < 64; m <<= 1) v += __shfl_xor(v, m, 64);
    return v;
}

// ---------- prep kernel ----------
// blocks 0..2047:  qvalsT[f*NQ + q] = float4{Qr, Qi, Qr^2+Qi^2, Qmag}
//   (TRANSPOSED [f][NQ] layout: main's lane=q loads become stride-16B
//    coalesced, 4 line-transactions/instr instead of 64)
// blocks 2048..2079: tableD[f*NB+b] = {-2Pr, -2Pi, |P|^2+eps, -softplus(qw)};
//                    tableM[f*NB+b] = mw
__global__ __launch_bounds__(256) void prep_kernel(
    const float* __restrict__ Q,        // [NQ][HD]
    const float* __restrict__ probes,   // [NB][HD]
    const float* __restrict__ angles,   // [NF]
    const float* __restrict__ qw,       // [NB][NF]
    const float* __restrict__ mw,       // [NB][NF]
    float4* __restrict__ qvalsT,        // [NF][NQ]
    float4* __restrict__ tableD,        // [NF][NB]
    float* __restrict__ tableM) {       // [NF][NB]
    if (blockIdx.x < 2048) {
        const int q  = blockIdx.x * 8 + (threadIdx.x >> 5);
        const int sl = threadIdx.x & 31;
        const float2* Q2 = (const float2*)Q;
        float2 a = Q2[q * 64 + sl];        // f = 2sl, 2sl+1 (real half)
        float2 c = Q2[q * 64 + 32 + sl];   // imag half
        float ss = a.x * a.x + a.y * a.y + c.x * c.x + c.y * c.y;
        #pragma unroll
        for (int m = 1; m < 32; m <<= 1) ss += __shfl_xor(ss, m);  // half-wave
        float inv = 1.0f / (sqrtf(ss) + EPSF);
        float Qr0 = a.x * inv, Qr1 = a.y * inv;
        float Qi0 = c.x * inv, Qi1 = c.y * inv;
        float B0 = Qr0 * Qr0 + Qi0 * Qi0;
        float B1 = Qr1 * Qr1 + Qi1 * Qi1;
        // scattered 16B stores; ~1M line-touches total over 2048 blocks -> ~2us
        qvalsT[(size_t)(2 * sl)     * NQ + q] = make_float4(Qr0, Qi0, B0, sqrtf(B0 + EPSF));
        qvalsT[(size_t)(2 * sl + 1) * NQ + q] = make_float4(Qr1, Qi1, B1, sqrtf(B1 + EPSF));
    } else {
        const int b    = (blockIdx.x - 2048) * 4 + (threadIdx.x >> 6);
        const int lane = threadIdx.x & 63;   // == f
        float p0 = probes[b * HD + lane];
        float p1 = probes[b * HD + 64 + lane];
        float ss = wave_allreduce_sum(p0 * p0 + p1 * p1);
        float inv = 1.0f / (sqrtf(ss) + EPSF);
        float pr = p0 * inv, pi = p1 * inv;
        float ang = angles[lane];
        float cc = cosf(ang), sn = sinf(ang);
        float Pr = pr * cc - pi * sn;
        float Pi = pr * sn + pi * cc;
        float x = qw[b * NF + lane];
        float sp = (x > 0.0f) ? (x + log1pf(expf(-x))) : log1pf(expf(x));
        tableD[lane * NB + b] = make_float4(-2.0f * Pr, -2.0f * Pi,
                                            Pr * Pr + Pi * Pi + EPSF, -sp);
        tableM[lane * NB + b] = mw[b * NF + lane];
    }
}

// ---------- main kernel ----------
// lane = q; QPT=4 q's per thread (q, q+64, q+128, q+192) so each LDS table
// broadcast read serves 256 items (R3's 1-q/thread made LDS reads the ~41us
// invariant floor); qvalsT [f][NQ] layout makes all 4 loads/f coalesced.
// BTILE=4 b's per block from LDS. Grid 512 -> 2 blocks/CU, ILP-rich body
// (96 VALU per 5 LDS + 4 VMEM per f-iter). VALU floor ~15.4us.
__global__ __launch_bounds__(256, 2) void main_kernel(
    const float4* __restrict__ tableD,  // [NF][NB]
    const float* __restrict__ tableM,   // [NF][NB]
    const float4* __restrict__ qvalsT,  // [NF][NQ]
    const float* __restrict__ bias,     // [NB]
    float* __restrict__ out) {          // [NQ][NB]
    __shared__ __align__(16) float4 ldsD[NF * BTILE];  // 4 KB
    __shared__ __align__(16) float4 ldsM[NF];          // 1 KB (4 b's per f)
    const int bt   = blockIdx.x & (NBT - 1);
    const int qblk = blockIdx.x / NBT;                 // 0..15
    const int wave = threadIdx.x >> 6;
    const int lane = threadIdx.x & 63;
    const int qbase = qblk * 1024 + wave * 256 + lane; // this thread's q0

    // stage table: 256 + 64 float4, coalesced
    {
        int idx = threadIdx.x;
        ldsD[idx] = tableD[(idx >> 2) * NB + bt * BTILE + (idx & 3)];
        if (idx < NF)  // tableM row f = 32 float4; take float4 #bt
            ldsM[idx] = ((const float4*)tableM)[idx * (NB / 4) + bt];
    }
    __syncthreads();

    float acc[QPT][BTILE];
    #pragma unroll
    for (int k = 0; k < QPT; ++k)
        #pragma unroll
        for (int i = 0; i < BTILE; ++i) acc[k][i] = 0.0f;

    const float4* __restrict__ qp = qvalsT + qbase;

    #pragma unroll 2
    for (int f = 0; f < NF; ++f) {
        float4 qv[QPT];
        #pragma unroll
        for (int k = 0; k < QPT; ++k)
            qv[k] = qp[(size_t)f * NQ + 64 * k];      // coalesced b128
        float4 t0 = ldsD[f * BTILE + 0];
        float4 t1 = ldsD[f * BTILE + 1];
        float4 t2 = ldsD[f * BTILE + 2];
        float4 t3 = ldsD[f * BTILE + 3];
        float4 tm4 = ldsM[f];
        #pragma unroll
        for (int k = 0; k < QPT; ++k) {
            #pragma unroll
            for (int bb = 0; bb < BTILE; ++bb) {
                float4 td = (bb == 0) ? t0 : (bb == 1) ? t1 : (bb == 2) ? t2 : t3;
                float t = td.z + qv[k].z;             // (|P|^2+eps) + |Qf|^2
                t = fmaf(td.y, qv[k].y, t);           // -2Pi*Qi
                t = fmaf(td.x, qv[k].x, t);           // -2Pr*Qr
                // t >= eps analytically; |.| folds into v_sqrt input modifier
                float d = __builtin_amdgcn_sqrtf(fabsf(t));
                acc[k][bb] = fmaf(td.w, d, acc[k][bb]);
                acc[k][bb] = fmaf((&tm4.x)[bb], qv[k].w, acc[k][bb]);
            }
        }
    }

    float4 bs = *(const float4*)&bias[bt * BTILE];
    #pragma unroll
    for (int k = 0; k < QPT; ++k) {
        float* op = out + (size_t)(qbase + 64 * k) * NB + bt * BTILE;
        *(float4*)op = make_float4(acc[k][0] + bs.x, acc[k][1] + bs.y,
                                   acc[k][2] + bs.z, acc[k][3] + bs.w);
    }
}

extern "C" void kernel_launch(void* const* d_in, const int* in_sizes, int n_in,
                              void* d_out, int out_size, void* d_ws, size_t ws_size,
                              hipStream_t stream) {
    const float* Q      = (const float*)d_in[0];   // [16384][128]
    const float* angles = (const float*)d_in[1];   // [64]
    const float* probes = (const float*)d_in[2];   // [128][128]
    const float* qw     = (const float*)d_in[3];   // [128][64]
    const float* mw     = (const float*)d_in[4];   // [128][64]
    const float* bias   = (const float*)d_in[5];   // [128]
    float* out = (float*)d_out;

    char* ws = (char*)d_ws;
    float4* tableD = (float4*)ws;                                    // 128 KB
    float*  tableM = (float*)(ws + NF * NB * sizeof(float4));        //  32 KB
    float4* qvalsT = (float4*)(ws + NF * NB * sizeof(float4)
                                  + NF * NB * sizeof(float));        //  16 MB

    prep_kernel<<<2048 + NB / 4, 256, 0, stream>>>(Q, probes, angles, qw, mw,
                                                   qvalsT, tableD, tableM);
    main_kernel<<<(NQ / (256 * QPT)) * NBT, 256, 0, stream>>>(tableD, tableM,
                                                              qvalsT, bias, out);
}